// Round 16
// baseline (72.334 us; speedup 1.0000x reference)
//
#include <hip/hip_runtime.h>
#include <hip/hip_bf16.h>

// Problem constants
#define NB   4      // batch
#define CCH  3      // channels
#define HW   320    // height == width
#define KS   5      // kernel/stride
#define LP   4096   // patches per batch (64*64)
#define KD   75     // c*k*k
#define NCH  12     // 16B chunks per patch row (96 bf16 = 12 x 8)

typedef __attribute__((ext_vector_type(4))) float f32x4;
typedef __attribute__((ext_vector_type(2))) float f32x2;
typedef __attribute__((ext_vector_type(8))) short bf16x8;

__device__ __forceinline__ ushort f2bf(float v) {
    __hip_bfloat16 h = __float2bfloat16(v);
    return __builtin_bit_cast(ushort, h);
}

// Kernel 1: build bf16 patch matrix in fragment-blocked layout
// p2[b][chunk][row] of 16B (8 bf16): chunk c holds patch cols 8c..8c+7
// (zero-padded past KD=75). Fully written every call (chunks 10,11 = zeros).
__global__ __launch_bounds__(256) void patch_kernel(const float* __restrict__ x,
                                                    ushort* __restrict__ p2) {
    int tid = threadIdx.x;
    int r   = blockIdx.x * 256 + tid;    // patch row 0..4095
    int c   = blockIdx.y;                // chunk 0..11
    int b   = blockIdx.z;
    int ph = r >> 6, pw = r & 63;
    const float* xb = x + (size_t)b * (CCH * HW * HW);

    bf16x8 v = {};
    if (c < 10) {
        #pragma unroll
        for (int j = 0; j < 8; ++j) {
            int k = c * 8 + j;
            float f = 0.f;
            if (k < KD) {
                int ch = k / 25, rem = k % 25;
                int ki = rem / 5, kj = rem % 5;
                f = xb[(ch * HW + ph * KS + ki) * HW + pw * KS + kj];
            }
            v[j] = (short)f2bf(f);
        }
    }
    *(bf16x8*)&p2[((size_t)(b * NCH + c) * LP + r) * 8] = v;
}

// Kernel 2: per-patch sumsq from the BLOCKED bf16 p2 (fully coalesced 16B
// loads; bf16 rounding adds ~0.05% rel err to max||p|| — well within the
// 2e-2 output threshold). One patch per thread; block max -> plain store.
__global__ __launch_bounds__(256) void normb_kernel(const ushort* __restrict__ p2,
                                                    float* __restrict__ blockmax) {
    int b = blockIdx.y;
    int r = blockIdx.x * 256 + threadIdx.x;     // patch row
    const ushort* pb = p2 + (size_t)b * NCH * LP * 8;

    float ss = 0.f;
    #pragma unroll
    for (int c = 0; c < 10; ++c) {              // chunks 10,11 are zeros
        bf16x8 v = *(const bf16x8*)&pb[((size_t)c * LP + r) * 8];
        #pragma unroll
        for (int j = 0; j < 8; ++j) {
            float f = __uint_as_float(((unsigned)(ushort)v[j]) << 16);
            ss = fmaf(f, f, ss);
        }
    }
    for (int off = 32; off; off >>= 1) ss = fmaxf(ss, __shfl_xor(ss, off, 64));
    __shared__ float sm[4];
    if ((threadIdx.x & 63) == 0) sm[threadIdx.x >> 6] = ss;
    __syncthreads();
    if (threadIdx.x == 0)
        blockmax[b * 16 + blockIdx.x] =
            fmaxf(fmaxf(sm[0], sm[1]), fmaxf(sm[2], sm[3]));
}

// Kernel 3: C = sigmoid((P P^T)/sqrt(max)). Block tile = 256 i-cols x 64
// j-rows; each WAVE owns 16 COMPLETE output rows (256 i x 16 j: m=16 A-frags,
// 1 B-frag, 48 MFMA, acc=64 VGPR) -> the transpose restage is wave-private
// (8KB), ZERO barriers, waves free-run so stores issue continuously.
// Sigmoid (exp+rcp, trans pipe) applied in-place on acc before staging.
// Stores: one contiguous 512B-aligned 512B run per instruction, nontemporal.
// Wave-local LDS write->read ordering via explicit s_waitcnt lgkmcnt(0).
// out[j][i] = dot(p_i,p_j) = C[j][i] exactly (symmetric, k-order identical).
__global__ __launch_bounds__(256) void gemm_kernel(const ushort* __restrict__ p2,
                                                   const float* __restrict__ blockmax,
                                                   float* __restrict__ out) {
    __shared__ float W[4][16][128];    // 32KB total: per-wave half-width restage

    int b  = blockIdx.z;
    int ti = blockIdx.x;   // i-tile 0..15 (fast dim)
    int tj = blockIdx.y;   // j-tile 0..63
    int tid = threadIdx.x;
    int lane = tid & 63;
    int w    = tid >> 6;
    int lrow = lane & 15;
    int lch  = lane >> 4;

    const ushort* pb = p2 + (size_t)b * NCH * LP * 8;
    int i0 = ti * 256;                 // block's i-cols (out cols)
    int jw = tj * 64 + w * 16;         // this wave's 16 j-rows (out rows)

    f32x4 acc[16] = {};
    #pragma unroll
    for (int ks = 0; ks < 3; ++ks) {
        const ushort* pk = pb + (size_t)(ks * 4 + lch) * LP * 8;  // chunk plane
        bf16x8 bfr = *(const bf16x8*)&pk[(size_t)(jw + lrow) * 8];
        #pragma unroll
        for (int m = 0; m < 16; ++m) {
            bf16x8 af = *(const bf16x8*)&pk[(size_t)(i0 + m * 16 + lrow) * 8];
            acc[m] = __builtin_amdgcn_mfma_f32_16x16x32_bf16(af, bfr, acc[m], 0, 0, 0);
        }
    }

    // fold per-batch max from the 16 block maxima (uniform scalar work)
    float mx = 0.f;
    #pragma unroll
    for (int i = 0; i < 16; ++i) mx = fmaxf(mx, blockmax[b * 16 + i]);
    float inv = 1.0f / sqrtf(mx);

    // sigmoid in place: all trans-pipe work done before any staging
    #pragma unroll
    for (int m = 0; m < 16; ++m)
        #pragma unroll
        for (int r = 0; r < 4; ++r)
            acc[m][r] = __builtin_amdgcn_rcpf(1.0f + __expf(-acc[m][r] * inv));

    float* ob = out + (size_t)b * LP * LP;
    float* Wp = &W[w][0][0];

    // Thread holds rows jr=lrow for i = m*16 + lch*4 + r. Two halves of 128
    // i-cols each: scatter (swizzled slots, uniform banks) -> wait -> gather
    // rows linearly -> 512B contiguous NT store per instruction.
    #pragma unroll
    for (int half = 0; half < 2; ++half) {
        asm volatile("s_waitcnt lgkmcnt(0)" ::: "memory");  // WAR vs prev half reads
        #pragma unroll
        for (int mm = 0; mm < 8; ++mm) {
            int sl = (mm * 4 + lch) ^ (lrow & 7);           // 16B slot 0..31
            *(f32x4*)&Wp[lrow * 128 + sl * 4] = acc[half * 8 + mm];
        }
        asm volatile("s_waitcnt lgkmcnt(0)" ::: "memory");  // RAW: writes visible
        #pragma unroll
        for (int r = 0; r < 16; ++r) {
            int sl = (lane >> 1) ^ (r & 7);                 // inverse swizzle
            f32x2 v = *(const f32x2*)&Wp[r * 128 + sl * 4 + (lane & 1) * 2];
            __builtin_nontemporal_store(v,
                (f32x2*)&ob[(size_t)(jw + r) * LP + i0 + half * 128 + lane * 2]);
        }
    }
}

extern "C" void kernel_launch(void* const* d_in, const int* in_sizes, int n_in,
                              void* d_out, int out_size, void* d_ws, size_t ws_size,
                              hipStream_t stream) {
    const float* x = (const float*)d_in[0];
    float* out = (float*)d_out;

    // ws layout: p2 bf16 blocked [NB][12][4096][8] (3.15 MB), blockmax f32[64].
    // Everything written-before-read with plain stores each call.
    ushort* p2 = (ushort*)d_ws;
    float* blockmax = (float*)((char*)d_ws + (size_t)NB * NCH * LP * 16);

    patch_kernel<<<dim3(LP / 256, NCH, NB), 256, 0, stream>>>(x, p2);
    normb_kernel<<<dim3(LP / 256, NB), 256, 0, stream>>>(p2, blockmax);
    gemm_kernel<<<dim3(16, 64, NB), 256, 0, stream>>>(p2, blockmax, out);
}

// Round 17
// 61.447 us; speedup vs baseline: 1.1772x; 1.1772x over previous
//
#include <hip/hip_runtime.h>
#include <hip/hip_bf16.h>

// Problem constants
#define NB   4      // batch
#define CCH  3      // channels
#define HW   320    // height == width
#define KS   5      // kernel/stride
#define LP   4096   // patches per batch (64*64)
#define KD   75     // c*k*k
#define NCH  12     // 16B chunks per patch row (96 bf16 = 12 x 8)

typedef __attribute__((ext_vector_type(4))) float f32x4;
typedef __attribute__((ext_vector_type(8))) short bf16x8;

__device__ __forceinline__ ushort f2bf(float v) {
    __hip_bfloat16 h = __float2bfloat16(v);
    return __builtin_bit_cast(ushort, h);
}

// Kernel 1: build bf16 patch matrix in fragment-blocked layout
// p2[b][chunk][row] of 16B (8 bf16): chunk c holds patch cols 8c..8c+7
// (zero-padded past KD=75). Fully written every call (chunks 10,11 = zeros).
__global__ __launch_bounds__(256) void patch_kernel(const float* __restrict__ x,
                                                    ushort* __restrict__ p2) {
    int tid = threadIdx.x;
    int r   = blockIdx.x * 256 + tid;    // patch row 0..4095
    int c   = blockIdx.y;                // chunk 0..11
    int b   = blockIdx.z;
    int ph = r >> 6, pw = r & 63;
    const float* xb = x + (size_t)b * (CCH * HW * HW);

    bf16x8 v = {};
    if (c < 10) {
        #pragma unroll
        for (int j = 0; j < 8; ++j) {
            int k = c * 8 + j;
            float f = 0.f;
            if (k < KD) {
                int ch = k / 25, rem = k % 25;
                int ki = rem / 5, kj = rem % 5;
                f = xb[(ch * HW + ph * KS + ki) * HW + pw * KS + kj];
            }
            v[j] = (short)f2bf(f);
        }
    }
    *(bf16x8*)&p2[((size_t)(b * NCH + c) * LP + r) * 8] = v;
}

// Kernel 2: per-patch sumsq from the BLOCKED bf16 p2 (fully coalesced 16B
// loads; bf16 rounding adds ~0.05% rel err to max||p|| — well within the
// 2e-2 output threshold). One patch per thread; block max -> plain store.
__global__ __launch_bounds__(256) void normb_kernel(const ushort* __restrict__ p2,
                                                    float* __restrict__ blockmax) {
    int b = blockIdx.y;
    int r = blockIdx.x * 256 + threadIdx.x;     // patch row
    const ushort* pb = p2 + (size_t)b * NCH * LP * 8;

    float ss = 0.f;
    #pragma unroll
    for (int c = 0; c < 10; ++c) {              // chunks 10,11 are zeros
        bf16x8 v = *(const bf16x8*)&pb[((size_t)c * LP + r) * 8];
        #pragma unroll
        for (int j = 0; j < 8; ++j) {
            float f = __uint_as_float(((unsigned)(ushort)v[j]) << 16);
            ss = fmaf(f, f, ss);
        }
    }
    for (int off = 32; off; off >>= 1) ss = fmaxf(ss, __shfl_xor(ss, off, 64));
    __shared__ float sm[4];
    if ((threadIdx.x & 63) == 0) sm[threadIdx.x >> 6] = ss;
    __syncthreads();
    if (threadIdx.x == 0)
        blockmax[b * 16 + blockIdx.x] =
            fmaxf(fmaxf(sm[0], sm[1]), fmaxf(sm[2], sm[3]));
}

// Kernel 3: C = sigmoid((P P^T)/sqrt(max)), 256-col x 64-row OUTPUT tile per
// block (symmetric-transpose trick, bit-identical). 4 waves side-by-side on i;
// each wave 64x64 = 4x4 fragments, K=96 in 3 steps, fragments loaded directly
// from blocked p2 (L2-resident). Per-block invmax fold from blockmax[16].
// SIGMOID HOISTED: exp+rcpf (trans pipe) applied in-place on acc right after
// the k-loop, OUTSIDE the barrier-bounded epilogue -> the barriered phases are
// pure LDS+store data movement. Epilogue: block-level LDS restage (32KB, 2
// phases of 32 j-rows, XOR-swizzled) -> every global store instruction writes
// ONE contiguous 1024B-aligned 1024B run; nontemporal (protects p2 L2).
__global__ __launch_bounds__(256) void gemm_kernel(const ushort* __restrict__ p2,
                                                   const float* __restrict__ blockmax,
                                                   float* __restrict__ out) {
    __shared__ float W[32][256];       // 32 KB restage buffer

    int b  = blockIdx.z;
    int ti = blockIdx.x;   // i-tile 0..15 (fast dim: sweeps cols in a j-band)
    int tj = blockIdx.y;   // j-tile 0..63
    int tid = threadIdx.x;
    int lane = tid & 63;
    int w    = tid >> 6;
    int lrow = lane & 15;
    int lch  = lane >> 4;

    const ushort* pb = p2 + (size_t)b * NCH * LP * 8;
    int i0 = ti * 256 + w * 64;         // this wave's i-rows (A side, out cols)
    int j0 = tj * 64;                   // block's j-rows (B side, out rows)

    f32x4 acc[4][4] = {};
    #pragma unroll
    for (int ks = 0; ks < 3; ++ks) {
        const ushort* pk = pb + (size_t)(ks * 4 + lch) * LP * 8;  // chunk plane
        bf16x8 af[4], bfr[4];
        #pragma unroll
        for (int m = 0; m < 4; ++m)
            af[m] = *(const bf16x8*)&pk[(size_t)(i0 + m * 16 + lrow) * 8];
        #pragma unroll
        for (int n = 0; n < 4; ++n)
            bfr[n] = *(const bf16x8*)&pk[(size_t)(j0 + n * 16 + lrow) * 8];
        #pragma unroll
        for (int m = 0; m < 4; ++m)
            #pragma unroll
            for (int n = 0; n < 4; ++n)
                acc[m][n] = __builtin_amdgcn_mfma_f32_16x16x32_bf16(af[m], bfr[n], acc[m][n], 0, 0, 0);
    }

    // fold per-batch max from the 16 block maxima (uniform scalar work)
    float mx = 0.f;
    #pragma unroll
    for (int i = 0; i < 16; ++i) mx = fmaxf(mx, blockmax[b * 16 + i]);
    float inv = 1.0f / sqrtf(mx);

    // sigmoid in place on acc: all trans-pipe work done before any barrier
    #pragma unroll
    for (int m = 0; m < 4; ++m)
        #pragma unroll
        for (int n = 0; n < 4; ++n)
            #pragma unroll
            for (int r = 0; r < 4; ++r)
                acc[m][n][r] = __builtin_amdgcn_rcpf(1.0f + __expf(-acc[m][n][r] * inv));

    float* ob = out + (size_t)b * LP * LP;

    // D frag (m,n): out row j = j0 + n*16 + (lane&15); out col i = i0' + m*16
    // + lch*4 + reg. Two phases, 32 j-rows each; barriered phases move data only.
    #pragma unroll
    for (int h = 0; h < 2; ++h) {
        if (h) __syncthreads();         // WAR: previous phase fully read
        #pragma unroll
        for (int np = 0; np < 2; ++np) {
            int n  = h * 2 + np;
            int jr = np * 16 + lrow;               // row 0..31 within phase
            #pragma unroll
            for (int m = 0; m < 4; ++m) {
                // logical 16B slot = w*16 + m*4 + lch; XOR low bits with jr
                int sl = w * 16 + (((m * 4 + lch) ^ (jr & 7)) & 15);
                *(f32x4*)&W[jr][sl * 4] = acc[m][n];
            }
        }
        __syncthreads();
        // each wave stores 8 rows; one instruction = 64 lanes x 16B = 1024B
        // contiguous, 1024B-aligned (row base = multiple of 16KB + ti*1024B)
        #pragma unroll
        for (int r8 = 0; r8 < 8; ++r8) {
            int row = w * 8 + r8;                  // 0..31
            f32x4 v = *(const f32x4*)&W[row][(lane ^ (row & 7)) * 4];
            __builtin_nontemporal_store(v,
                (f32x4*)&ob[(size_t)(j0 + h * 32 + row) * LP + ti * 256 + lane * 4]);
        }
    }
}

extern "C" void kernel_launch(void* const* d_in, const int* in_sizes, int n_in,
                              void* d_out, int out_size, void* d_ws, size_t ws_size,
                              hipStream_t stream) {
    const float* x = (const float*)d_in[0];
    float* out = (float*)d_out;

    // ws layout: p2 bf16 blocked [NB][12][4096][8] (3.15 MB), blockmax f32[64].
    // Everything written-before-read with plain stores each call.
    ushort* p2 = (ushort*)d_ws;
    float* blockmax = (float*)((char*)d_ws + (size_t)NB * NCH * LP * 16);

    patch_kernel<<<dim3(LP / 256, NCH, NB), 256, 0, stream>>>(x, p2);
    normb_kernel<<<dim3(LP / 256, NB), 256, 0, stream>>>(p2, blockmax);
    gemm_kernel<<<dim3(16, 64, NB), 256, 0, stream>>>(p2, blockmax, out);
}